// Round 12
// baseline (582.500 us; speedup 1.0000x reference)
//
#include <hip/hip_runtime.h>
#include <math.h>

#define Bn 16
#define Sn 512
#define Hn 768
#define NHn 12
#define DHn 64
#define In 3072
#define TOK (Bn*Sn)

typedef unsigned short u16;
typedef short bf16x8 __attribute__((ext_vector_type(8)));
typedef short bf16x4 __attribute__((ext_vector_type(4)));
typedef float f32x4 __attribute__((ext_vector_type(4)));
typedef unsigned int u32x2 __attribute__((ext_vector_type(2)));

__device__ __forceinline__ u16 f2bf(float x) {
    union { float f; unsigned u; } v; v.f = x;
    unsigned r = v.u + 0x7FFF + ((v.u >> 16) & 1);
    return (u16)(r >> 16);
}
__device__ __forceinline__ float bf2f(u16 u) {
    union { unsigned u; float f; } v; v.u = ((unsigned)u) << 16; return v.f;
}
// pack two f32 -> one u32 of 2 bf16 (RNE, bit-identical to f2bf pair; pure C, no asm)
__device__ __forceinline__ unsigned pk2bf(float lo, float hi) {
    union { float f; unsigned u; } a, b; a.f = lo; b.f = hi;
    unsigned rl = a.u + 0x7FFFu + ((a.u >> 16) & 1u);
    unsigned rh = b.u + 0x7FFFu + ((b.u >> 16) & 1u);
    return (rh & 0xFFFF0000u) | (rl >> 16);
}

// 16-lane-group reduce via DPP (VALU pipe; replaces ds_bpermute-based __shfl_xor).
__device__ __forceinline__ float dpp_max16(float x) {
    union { float f; int i; } a, b;
    a.f = x; b.i = __builtin_amdgcn_update_dpp(0, a.i, 0xB1, 0xF, 0xF, true); x = fmaxf(x, b.f);
    a.f = x; b.i = __builtin_amdgcn_update_dpp(0, a.i, 0x4E, 0xF, 0xF, true); x = fmaxf(x, b.f);
    a.f = x; b.i = __builtin_amdgcn_update_dpp(0, a.i, 0x124, 0xF, 0xF, true); x = fmaxf(x, b.f);
    a.f = x; b.i = __builtin_amdgcn_update_dpp(0, a.i, 0x128, 0xF, 0xF, true); x = fmaxf(x, b.f);
    return x;
}
__device__ __forceinline__ float dpp_sum16(float x) {
    union { float f; int i; } a, b;
    a.f = x; b.i = __builtin_amdgcn_update_dpp(0, a.i, 0xB1, 0xF, 0xF, true); x += b.f;
    a.f = x; b.i = __builtin_amdgcn_update_dpp(0, a.i, 0x4E, 0xF, 0xF, true); x += b.f;
    a.f = x; b.i = __builtin_amdgcn_update_dpp(0, a.i, 0x124, 0xF, 0xF, true); x += b.f;
    a.f = x; b.i = __builtin_amdgcn_update_dpp(0, a.i, 0x128, 0xF, 0xF, true); x += b.f;
    return x;
}

// async global->LDS DMA, 16 B/lane; dest = wave-uniform base + lane*16
__device__ __forceinline__ void gl_lds16(const void* g, void* s) {
    __builtin_amdgcn_global_load_lds((const __attribute__((address_space(1))) void*)g,
                                     (__attribute__((address_space(3))) void*)s, 16, 0, 0);
}

// ---------------- fused prep: 8 weight transposes + 2 cvts + bias pack, one launch ----------------
struct TJobs {
    const float* src[8];
    u16* dst[8];
    int K[8];
    int N[8];
    int bstart[9];
};

__global__ __launch_bounds__(256) void k_prep(TJobs J, const float* __restrict__ hs, u16* __restrict__ X16,
                                              const float* __restrict__ pos, u16* __restrict__ pos16,
                                              const float* __restrict__ bq, const float* __restrict__ bk,
                                              const float* __restrict__ bv, float* __restrict__ bqkv) {
    __shared__ float tile[32][33];
    int bid = blockIdx.x;
    int T8 = J.bstart[8];
    int tx = threadIdx.x, ty = threadIdx.y;  // (32,8)
    int t = ty * 32 + tx;
    if (bid < T8) {
        // transpose job: f32[K,N] -> bf16[N,K]
        int ji = 0;
        #pragma unroll
        for (int q = 0; q < 8; q++) if (bid >= J.bstart[q + 1]) ji = q + 1;
        const float* W = J.src[ji];
        u16* Wt = J.dst[ji];
        int K = J.K[ji], N = J.N[ji];
        int local = bid - J.bstart[ji];
        int nbx = N >> 5;
        int bx = local % nbx, by = local / nbx;
        int n0 = bx * 32, k0 = by * 32;
        #pragma unroll
        for (int i = 0; i < 32; i += 8)
            tile[ty + i][tx] = W[(size_t)(k0 + ty + i) * N + n0 + tx];
        __syncthreads();
        #pragma unroll
        for (int i = 0; i < 32; i += 8)
            Wt[(size_t)(n0 + ty + i) * K + k0 + tx] = f2bf(tile[tx][ty + i]);
    } else if (bid < T8 + 3072) {
        int i = ((bid - T8) * 256 + t) * 8;   // n = TOK*Hn = 6291456 exactly
        float4 a = *(const float4*)(hs + i);
        float4 b = *(const float4*)(hs + i + 4);
        bf16x8 o;
        o[0] = (short)f2bf(a.x); o[1] = (short)f2bf(a.y); o[2] = (short)f2bf(a.z); o[3] = (short)f2bf(a.w);
        o[4] = (short)f2bf(b.x); o[5] = (short)f2bf(b.y); o[6] = (short)f2bf(b.z); o[7] = (short)f2bf(b.w);
        *(bf16x8*)(X16 + i) = o;
    } else if (bid < T8 + 3456) {
        int i = ((bid - T8 - 3072) * 256 + t) * 8;   // n = 1024*768 = 786432 exactly
        float4 a = *(const float4*)(pos + i);
        float4 b = *(const float4*)(pos + i + 4);
        bf16x8 o;
        o[0] = (short)f2bf(a.x); o[1] = (short)f2bf(a.y); o[2] = (short)f2bf(a.z); o[3] = (short)f2bf(a.w);
        o[4] = (short)f2bf(b.x); o[5] = (short)f2bf(b.y); o[6] = (short)f2bf(b.z); o[7] = (short)f2bf(b.w);
        *(bf16x8*)(pos16 + i) = o;
    } else {
        int i = (bid - T8 - 3456) * 256 + t;
        if (i < 2304) bqkv[i] = (i < 768) ? bq[i] : (i < 1536 ? bk[i - 768] : bv[i - 1536]);
    }
}

// ---------------- bf16 MFMA GEMM: BK=64, global_load_lds, XOR swizzle, XCD-affinity remap ----------------
#define GM_BF16 0
#define GM_F32 1
#define GM_GELU_BF16 2
#define GM_POSH 3   // write bf16 to [h][r][d]: h=col>>6, d=col&63, idx=h*65536+row*64+d
#define GM_QKV 4    // cols<1536 -> qkv[row*1536+col] bf16; cols>=1536 -> Vt scatter (V transpose fused)

template<int NT>
__global__ __launch_bounds__(256) void k_gemm_t(const u16* __restrict__ A, const u16* __restrict__ Bt,
                                                const float* __restrict__ bias, void* __restrict__ Cout,
                                                void* __restrict__ Cout2,
                                                int M, int N, int K, int mode) {
    constexpr int TN = NT / 32;
    __shared__ __align__(16) u16 sA[128 * 64];
    __shared__ __align__(16) u16 sB[NT * 64];
    int tid = threadIdx.x;
    int wave = tid >> 6, lane = tid & 63;
    int lane16 = lane & 15, quad = lane >> 4;

    int nb = gridDim.x;
    int flat = blockIdx.y * nb + blockIdx.x;
    int c = flat & 7, g = flat >> 3;
    int mt = c + 8 * (g / nb), nt = g % nb;   // requires gridDim.y % 8 == 0
    int m0 = mt * 128, n0 = nt * NT;

    int wm = (wave >> 1) * 64;
    int wn = (wave & 1) * (NT / 2);
    f32x4 acc[4][TN] = {};

    int r_st = lane >> 3;
    int c8p = lane & 7;

    for (int k0 = 0; k0 < K; k0 += 64) {
        __syncthreads();
        #pragma unroll
        for (int I = 0; I < 4; I++) {
            int Ii = wave + I * 4;
            int r = Ii * 8 + r_st;
            int c8 = c8p ^ (r & 7);
            gl_lds16(&A[(size_t)(m0 + r) * K + k0 + c8 * 8], &sA[Ii * 512]);
        }
        #pragma unroll
        for (int I = 0; I < NT / 32; I++) {
            int Ii = wave + I * 4;
            int r = Ii * 8 + r_st;
            int c8 = c8p ^ (r & 7);
            gl_lds16(&Bt[(size_t)(n0 + r) * K + k0 + c8 * 8], &sB[Ii * 512]);
        }
        __syncthreads();
        #pragma unroll
        for (int h = 0; h < 2; h++) {
            bf16x8 af[4], bfr[TN];
            #pragma unroll
            for (int t = 0; t < 4; t++) {
                int R = wm + t * 16 + lane16;
                af[t] = *(const bf16x8*)&sA[R * 64 + (((4 * h + quad) ^ (R & 7)) << 3)];
            }
            #pragma unroll
            for (int t = 0; t < TN; t++) {
                int R = wn + t * 16 + lane16;
                bfr[t] = *(const bf16x8*)&sB[R * 64 + (((4 * h + quad) ^ (R & 7)) << 3)];
            }
            #pragma unroll
            for (int tm = 0; tm < 4; tm++)
                #pragma unroll
                for (int tn = 0; tn < TN; tn++)
                    acc[tm][tn] = __builtin_amdgcn_mfma_f32_16x16x32_bf16(af[tm], bfr[tn], acc[tm][tn], 0, 0, 0);
        }
    }

    float* Cf = (float*)Cout;
    u16* Ch = (u16*)Cout;
    #pragma unroll
    for (int tm = 0; tm < 4; tm++) {
        #pragma unroll
        for (int tn = 0; tn < TN; tn++) {
            int col = n0 + wn + tn * 16 + lane16;
            float bv_ = bias ? bias[col] : 0.f;
            #pragma unroll
            for (int r = 0; r < 4; r++) {
                int row = m0 + wm + tm * 16 + quad * 4 + r;
                float v = acc[tm][tn][r] + bv_;
                if (mode == GM_GELU_BF16) {
                    v = 0.5f * v * (1.f + erff(v * 0.70710678118654752f));
                    Ch[(size_t)row * N + col] = f2bf(v);
                } else if (mode == GM_BF16) {
                    Ch[(size_t)row * N + col] = f2bf(v);
                } else if (mode == GM_POSH) {
                    Ch[(((size_t)col >> 6) << 16) + ((size_t)row << 6) + (col & 63)] = f2bf(v);
                } else if (mode == GM_QKV) {
                    if (col < 1536) {
                        Ch[(size_t)row * 1536 + col] = f2bf(v);
                    } else {
                        // V transpose fused: Vt[(b*12+h)*64 + d][j], b=row>>9, h=(col-1536)>>6, d=col&63, j=row&511
                        u16* Vt_ = (u16*)Cout2;
                        int zz = (row >> 9) * 12 + ((col - 1536) >> 6);
                        Vt_[(((size_t)zz * 64 + (col & 63)) << 9) + (row & 511)] = f2bf(v);
                    }
                } else {
                    Cf[(size_t)row * N + col] = v;
                }
            }
        }
    }
}

// ---------------- fused disentangled attention, XCD-affinity with TEMPORAL z-grouping ----------------
// flat = y*8+x; xcd=flat&7; g=flat>>3; z = xcd*24 + (g>>3); i0 = (g&7)*64
// LDS (u16 idx): sK [0,4096) (Q stage at start, P surface later), sV [4096,8192),
// sPK [8192,16384), sPQ [16384,24576); scatter alias s1 [8192,16896), s2 [16896,25600).
//
// R3 HYBRID decomposition + R4 DPP softmax + R7 pk2bf/setprio (verified).
// R12: qkv stride 2304->1536 (V cols no longer stored in qkv; the qkv GEMM writes V
// directly into Vt layout via GM_QKV, eliminating the k_vt transpose kernel).
// R10's counted-vmcnt staging reverted (measured neutral; plain barriers restored).
__global__ __launch_bounds__(256, 3) void k_attn(const u16* __restrict__ qkv, const u16* __restrict__ poskR,
                                                 const u16* __restrict__ posqR, const u16* __restrict__ Vt,
                                                 const float* __restrict__ mask, u16* __restrict__ ctx) {
    __shared__ __align__(16) u16 smem[25600];
    u16* sK = smem;
    u16* sV = smem + 4096;
    u16* sPK = smem + 8192;
    u16* s1 = smem + 8192;
    u16* s2 = smem + 16896;

    int flat = blockIdx.y * gridDim.x + blockIdx.x;   // grid (8,192)
    int xcd = flat & 7, g = flat >> 3;                // g in [0,192)
    int z = xcd * 24 + (g >> 3);
    int i0 = (g & 7) * 64;
    int b = z / NHn, h = z % NHn;
    int tid = threadIdx.x, wave = tid >> 6, lane = tid & 63;
    int lane16 = lane & 15, quad = lane >> 4;
    int lr = lane >> 3, lc8 = lane & 7;
    int c8v = (lc8 ^ lr) << 3;   // lane-const swizzled chunk offset (r&7 == lr for all chunks)

    // ---- stage Q once (into sK), read own-wave A-fragments ----
    #pragma unroll
    for (int I = 0; I < 2; I++) {
        int CI = wave * 2 + I;
        int r = CI * 8 + lr;
        gl_lds16(&qkv[(size_t)(b * Sn + i0 + r) * 1536 + h * 64 + c8v], &sK[CI * 512]);
    }
    __syncthreads();
    int Rq = wave * 16 + lane16;
    bf16x8 aqw0 = *(const bf16x8*)&sK[Rq * 64 + (((quad    ) ^ (Rq & 7)) << 3)];
    bf16x8 aqw1 = *(const bf16x8*)&sK[Rq * 64 + (((quad + 4) ^ (Rq & 7)) << 3)];

    // ---- hoisted staging pointers ----
    const u16* kp0 = qkv + (size_t)(b * Sn + wave * 8 + lr) * 1536 + 768 + h * 64 + c8v;
    const u16* kp1 = qkv + (size_t)(b * Sn + (4 + wave) * 8 + lr) * 1536 + 768 + h * 64 + c8v;
    const u16* vp0 = Vt + ((size_t)z * 64 + wave * 8 + lr) * Sn + c8v;
    const u16* vp1 = Vt + ((size_t)z * 64 + (4 + wave) * 8 + lr) * Sn + c8v;
    const u16* pkb = poskR + (size_t)h * 65536 + c8v;
    const u16* pqb = posqR + (size_t)h * 65536 + c8v;
    int rl0 = wave * 8 + lr;   // pos row lane-term for chunk group q: rl0 + 32q

    f32x4 o[4] = {};
    float m_[4] = {-1e30f, -1e30f, -1e30f, -1e30f};
    float l_[4] = {};
    const float scale = 0.07216878364870323f;  // 1/sqrt(3*64)

    for (int jt = 0; jt < 8; jt++) {
        int j0 = jt * 64;
        int r0pk = i0 - j0 + 449, r0pq = j0 - i0 + 449;
        __syncthreads();  // prior iter's P/sV/s1/s2 uses complete before restage
        // ---- stage K(8) V(8) PK(16) PQ(16) 1KB-chunks, 12 DMA per wave ----
        gl_lds16(kp0, &smem[(wave    ) * 512]);  kp0 += 64 * 1536;
        gl_lds16(kp1, &smem[(4 + wave) * 512]);  kp1 += 64 * 1536;
        gl_lds16(vp0, &smem[(8 + wave) * 512]);  vp0 += 64;
        gl_lds16(vp1, &smem[(12 + wave) * 512]); vp1 += 64;
        #pragma unroll
        for (int q = 0; q < 4; q++) {
            int rl = rl0 + 32 * q;
            int rowk = min(r0pk + rl, 1023);
            int rowq = min(r0pq + rl, 1023);
            gl_lds16(pkb + ((size_t)rowk << 6), &smem[(16 + 4 * q + wave) * 512]);
            gl_lds16(pqb + ((size_t)rowq << 6), &smem[(32 + 4 * q + wave) * 512]);
        }
        float mv[4];
        #pragma unroll
        for (int tn = 0; tn < 4; tn++) mv[tn] = mask[(size_t)b * Sn + j0 + tn * 16 + lane16];
        __syncthreads();  // DMA drain + barrier

        // ---- MFMA phase ----
        f32x4 cc[4];
        u32x2 w1h[8], w2h[4][2];
        __builtin_amdgcn_s_setprio(1);
        // cc + p2c (pos-row-partitioned): kf as cc-B and p2c-A, own-band pqf
        {
            bf16x8 pqf0[2], pqf1[2];
            #pragma unroll
            for (int t = 0; t < 2; t++) {
                int R = wave * 32 + t * 16 + lane16;
                pqf0[t] = *(const bf16x8*)&sPK[8192 + R * 64 + (((quad    ) ^ (R & 7)) << 3)];
                pqf1[t] = *(const bf16x8*)&sPK[8192 + R * 64 + (((quad + 4) ^ (R & 7)) << 3)];
            }
            #pragma unroll
            for (int mb = 0; mb < 4; mb++) {
                int R = mb * 16 + lane16;
                bf16x8 kf0 = *(const bf16x8*)&sK[R * 64 + (((quad    ) ^ (R & 7)) << 3)];
                bf16x8 kf1 = *(const bf16x8*)&sK[R * 64 + (((quad + 4) ^ (R & 7)) << 3)];
                f32x4 x = {};
                x = __builtin_amdgcn_mfma_f32_16x16x32_bf16(aqw0, kf0, x, 0, 0, 0);
                x = __builtin_amdgcn_mfma_f32_16x16x32_bf16(aqw1, kf1, x, 0, 0, 0);
                cc[mb] = x;
                #pragma unroll
                for (int t = 0; t < 2; t++) {
                    f32x4 y = {};
                    y = __builtin_amdgcn_mfma_f32_16x16x32_bf16(kf0, pqf0[t], y, 0, 0, 0);
                    y = __builtin_amdgcn_mfma_f32_16x16x32_bf16(kf1, pqf1[t], y, 0, 0, 0);
                    u32x2 pp;
                    pp[0] = pk2bf(y[0], y[1]);
                    pp[1] = pk2bf(y[2], y[3]);
                    w2h[mb][t] = pp;
                }
            }
        }
        // c2p (i-partitioned, R0-style): own aqw x all 8 pos-row-tiles of sPK
        #pragma unroll
        for (int tr = 0; tr < 8; tr++) {
            int R = tr * 16 + lane16;
            bf16x8 b0 = *(const bf16x8*)&sPK[R * 64 + (((quad    ) ^ (R & 7)) << 3)];
            bf16x8 b1 = *(const bf16x8*)&sPK[R * 64 + (((quad + 4) ^ (R & 7)) << 3)];
            f32x4 x = {};
            x = __builtin_amdgcn_mfma_f32_16x16x32_bf16(aqw0, b0, x, 0, 0, 0);
            x = __builtin_amdgcn_mfma_f32_16x16x32_bf16(aqw1, b1, x, 0, 0, 0);
            u32x2 oo;
            oo[0] = pk2bf(x[0], x[1]);
            oo[1] = pk2bf(x[2], x[3]);
            w1h[tr] = oo;
        }
        __builtin_amdgcn_s_setprio(0);
        __syncthreads();  // pos-window reads done; sPK/sPQ become s1/s2

        // ---- diagonal scatter: s1 per-wave COLUMNS (R0), s2 per-wave ROWS (R2) ----
        int sw = wave * 16 + quad * 4;
        #pragma unroll
        for (int tr = 0; tr < 8; tr++)
            *(u32x2*)&s1[(tr * 16 + lane16) * 68 + sw] = w1h[tr];
        #pragma unroll
        for (int mb = 0; mb < 4; mb++)
            #pragma unroll
            for (int t = 0; t < 2; t++) {
                int p = wave * 32 + t * 16 + lane16;
                int ci = mb * 16 + quad * 4;
                *(u32x2*)&s2[p * 68 + ci] = w2h[mb][t];
            }
        __syncthreads();

        // ---- gather + online softmax (DPP reduce) + P write (dead sK, swizzled) + PV ----
        float S[4][4];
        #pragma unroll
        for (int tn = 0; tn < 4; tn++) {
            int jL = tn * 16 + lane16;
            #pragma unroll
            for (int r = 0; r < 4; r++) {
                int iL = wave * 16 + quad * 4 + r;
                float v = cc[tn][r] + bf2f(s1[(iL - jL + 63) * 68 + iL])
                                    + bf2f(s2[(jL - iL + 63) * 68 + jL]);
                v *= scale;
                S[tn][r] = (mv[tn] > 0.f) ? v : -1e9f;
            }
        }
        #pragma unroll
        for (int r = 0; r < 4; r++) {
            float mx = fmaxf(fmaxf(S[0][r], S[1][r]), fmaxf(S[2][r], S[3][r]));
            mx = dpp_max16(mx);
            float mnew = fmaxf(m_[r], mx);
            float alpha = __expf(m_[r] - mnew);
            float p0 = __expf(S[0][r] - mnew), p1 = __expf(S[1][r] - mnew);
            float p2 = __expf(S[2][r] - mnew), p3 = __expf(S[3][r] - mnew);
            float ps = p0 + p1 + p2 + p3;
            ps = dpp_sum16(ps);
            l_[r] = l_[r] * alpha + ps;
            m_[r] = mnew;
            #pragma unroll
            for (int dn = 0; dn < 4; dn++) o[dn][r] *= alpha;
            int prow = wave * 16 + quad * 4 + r;
            int pl = lane16 >> 3, pc = lane16 & 7;
            sK[prow * 64 + (((0 + pl) ^ (prow & 7)) << 3) + pc] = f2bf(p0);
            sK[prow * 64 + (((2 + pl) ^ (prow & 7)) << 3) + pc] = f2bf(p1);
            sK[prow * 64 + (((4 + pl) ^ (prow & 7)) << 3) + pc] = f2bf(p2);
            sK[prow * 64 + (((6 + pl) ^ (prow & 7)) << 3) + pc] = f2bf(p3);
        }
        // PV: A rows are this wave's own rows (same-wave LDS RAW is in-order safe)
        int Rp = wave * 16 + lane16;
        bf16x8 aP0 = *(const bf16x8*)&sK[Rp * 64 + (((quad    ) ^ (Rp & 7)) << 3)];
        bf16x8 aP1 = *(const bf16x8*)&sK[Rp * 64 + (((quad + 4) ^ (Rp & 7)) << 3)];
        __builtin_amdgcn_s_setprio(1);
        #pragma unroll
        for (int dn = 0; dn < 4; dn++) {
            int R = dn * 16 + lane16;
            bf16x8 b0 = *(const bf16x8*)&sV[R * 64 + (((quad    ) ^ (R & 7)) << 3)];
            bf16x8 b1 = *(const bf16x8*)&sV[R * 64 + (((quad + 4) ^ (R & 7)) << 3)];
            o[dn] = __builtin_amdgcn_mfma_f32_16x16x32_bf16(aP0, b0, o[dn], 0, 0, 0);
            o[dn] = __builtin_amdgcn_mfma_f32_16x16x32_bf16(aP1, b1, o[dn], 0, 0, 0);
        }
        __builtin_amdgcn_s_setprio(0);
    }

    // ---- normalize + store ctx ----
    #pragma unroll
    for (int r = 0; r < 4; r++) {
        float inv = 1.f / l_[r];
        int row = i0 + wave * 16 + quad * 4 + r;
        #pragma unroll
        for (int dn = 0; dn < 4; dn++)
            ctx[(size_t)(b * Sn + row) * Hn + h * 64 + dn * 16 + lane16] = f2bf(o[dn][r] * inv);
    }
}

// ---------------- residual + layernorm (optionally also bf16 copy) ----------------
__global__ __launch_bounds__(256) void k_ln(const float* __restrict__ x1, const float* __restrict__ x2,
                                            const float* __restrict__ g, const float* __restrict__ bb,
                                            float* __restrict__ outf, u16* __restrict__ outh) {
    int row = blockIdx.x, t = threadIdx.x;
    const float* p1 = x1 + (size_t)row * Hn;
    const float* p2 = x2 + (size_t)row * Hn;
    float x[3], s1 = 0.f, s2 = 0.f;
    #pragma unroll
    for (int i = 0; i < 3; i++) {
        int c = t + i * 256;
        float v = p1[c] + p2[c];
        x[i] = v; s1 += v; s2 += v * v;
    }
    for (int off = 32; off; off >>= 1) { s1 += __shfl_xor(s1, off); s2 += __shfl_xor(s2, off); }
    __shared__ float a1[4], a2[4];
    if ((t & 63) == 0) { a1[t >> 6] = s1; a2[t >> 6] = s2; }
    __syncthreads();
    s1 = a1[0] + a1[1] + a1[2] + a1[3];
    s2 = a2[0] + a2[1] + a2[2] + a2[3];
    float mu = s1 * (1.f / 768.f);
    float var = s2 * (1.f / 768.f) - mu * mu;
    float rs = rsqrtf(var + 1e-7f);
    #pragma unroll
    for (int i = 0; i < 3; i++) {
        int c = t + i * 256;
        float y = (x[i] - mu) * rs * g[c] + bb[c];
        outf[(size_t)row * Hn + c] = y;
        if (outh) outh[(size_t)row * Hn + c] = f2bf(y);
    }
}

extern "C" void kernel_launch(void* const* d_in, const int* in_sizes, int n_in,
                              void* d_out, int out_size, void* d_ws, size_t ws_size,
                              hipStream_t stream) {
    const float* hs   = (const float*)d_in[0];
    const float* mask = (const float*)d_in[1];
    const float* pos  = (const float*)d_in[2];
    const float* Wq = (const float*)d_in[3],  *bq = (const float*)d_in[4];
    const float* Wk = (const float*)d_in[5],  *bk = (const float*)d_in[6];
    const float* Wv = (const float*)d_in[7],  *bv = (const float*)d_in[8];
    const float* Wpk = (const float*)d_in[9], *Wpq = (const float*)d_in[10];
    const float* Wo = (const float*)d_in[11], *bo = (const float*)d_in[12];
    const float* g1 = (const float*)d_in[13], *b1ln = (const float*)d_in[14];
    const float* W1 = (const float*)d_in[15], *b1f = (const float*)d_in[16];
    const float* W2 = (const float*)d_in[17], *b2f = (const float*)d_in[18];
    const float* g2 = (const float*)d_in[19], *b2ln = (const float*)d_in[20];
    float* out = (float*)d_out;

    char* w = (char*)d_ws;
    u16*  X16    = (u16*)w;                 w += 12582912;   // [8192,768] bf16
    u16*  pos16  = (u16*)w;                 w += 1572864;    // [1024,768] bf16
    u16*  WqkvT  = (u16*)w;                 w += 3538944;    // [2304,768] bf16
    float* bqkv  = (float*)w;               w += 9216;       // [2304]
    u16*  WoT    = (u16*)w;                 w += 1179648;    // [768,768]
    u16*  W1T    = (u16*)w;                 w += 4718592;    // [3072,768]
    u16*  W2T    = (u16*)w;                 w += 4718592;    // [768,3072]
    u16*  WpkT   = (u16*)w;                 w += 1179648;
    u16*  WpqT   = (u16*)w;                 w += 1179648;    // adjacent to WpkT (merged pos GEMM)
    u16*  posk   = (u16*)w;                 w += 1572864;    // [12][1024][64] bf16 per-head
    u16*  posq   = (u16*)w;                 w += 1572864;    // adjacent to posk (GM_POSH spans both)
    u16*  qkv    = (u16*)w;                 w += 25165824;   // [8192,1536] bf16 (Q|K only; V goes to Vt)
    u16*  Vt     = (u16*)w;                 w += 12582912;   // [192,64,512] bf16 (written by qkv GEMM)
    char* big    = w;                       w += 100663296;
    float* attnout = (float*)w;             w += 25165824;   // [8192,768] f32
    // lifetime-disjoint carve-up of `big`:
    u16*  ctx  = (u16*)big;                        // [0, 12.6MB)  written by k_attn
    float* h1f = (float*)(big + 16777216);         // [16MB, 42MB) after Wo+LN1
    u16*  ffn1 = (u16*)(big + 50331648);           // [48MB, 98.6MB)
    u16*  h1h  = X16;                              // X16 dead after qkv GEMM
    float* ffn2 = attnout;                         // attnout dead after LN1

    // prep: fused converts + weight transposes + bias pack (one launch)
    TJobs J;
    J.src[0] = Wq;  J.dst[0] = WqkvT;           J.K[0] = 768;  J.N[0] = 768;
    J.src[1] = Wk;  J.dst[1] = WqkvT + 589824;  J.K[1] = 768;  J.N[1] = 768;
    J.src[2] = Wv;  J.dst[2] = WqkvT + 1179648; J.K[2] = 768;  J.N[2] = 768;
    J.src[3] = Wo;  J.dst[3] = WoT;             J.K[3] = 768;  J.N[3] = 768;
    J.src[4] = Wpk; J.dst[4] = WpkT;            J.K[4] = 768;  J.N[4] = 768;
    J.src[5] = Wpq; J.dst[5] = WpqT;            J.K[5] = 768;  J.N[5] = 768;
    J.src[6] = W1;  J.dst[6] = W1T;             J.K[6] = 768;  J.N[6] = 3072;
    J.src[7] = W2;  J.dst[7] = W2T;             J.K[7] = 3072; J.N[7] = 768;
    J.bstart[0] = 0;
    for (int i = 0; i < 8; i++) J.bstart[i + 1] = J.bstart[i] + (J.N[i] >> 5) * (J.K[i] >> 5);
    k_prep<<<J.bstart[8] + 3465, dim3(32, 8), 0, stream>>>(J, hs, X16, pos, pos16, bq, bk, bv, bqkv);

    // projections; qkv GEMM writes Q|K row-major and V directly into Vt (k_vt fused away)
    k_gemm_t<128><<<dim3(18, 64), 256, 0, stream>>>(X16, WqkvT, bqkv, qkv, Vt, TOK, 2304, 768, GM_QKV);
    k_gemm_t<128><<<dim3(12, 8), 256, 0, stream>>>(pos16, WpkT, nullptr, posk, nullptr, 1024, 1536, 768, GM_POSH);

    // fused attention
    k_attn<<<dim3(8, 192), 256, 0, stream>>>(qkv, posk, posq, Vt, mask, ctx);
    k_gemm_t<64><<<dim3(12, 64), 256, 0, stream>>>(ctx, WoT, bo, attnout, nullptr, TOK, 768, 768, GM_F32);
    k_ln<<<TOK, 256, 0, stream>>>(hs, attnout, g1, b1ln, h1f, h1h);

    // FFN
    k_gemm_t<128><<<dim3(24, 64), 256, 0, stream>>>(h1h, W1T, b1f, ffn1, nullptr, TOK, 3072, 768, GM_GELU_BF16);
    k_gemm_t<64><<<dim3(12, 64), 256, 0, stream>>>(ffn1, W2T, b2f, ffn2, nullptr, TOK, 768, 3072, GM_F32);
    k_ln<<<TOK, 256, 0, stream>>>(h1f, ffn2, g2, b2ln, out, nullptr);
}

// Round 14
// 474.616 us; speedup vs baseline: 1.2273x; 1.2273x over previous
//
#include <hip/hip_runtime.h>
#include <math.h>

#define Bn 16
#define Sn 512
#define Hn 768
#define NHn 12
#define DHn 64
#define In 3072
#define TOK (Bn*Sn)

typedef unsigned short u16;
typedef short bf16x8 __attribute__((ext_vector_type(8)));
typedef short bf16x4 __attribute__((ext_vector_type(4)));
typedef float f32x4 __attribute__((ext_vector_type(4)));
typedef unsigned int u32x2 __attribute__((ext_vector_type(2)));

__device__ __forceinline__ u16 f2bf(float x) {
    union { float f; unsigned u; } v; v.f = x;
    unsigned r = v.u + 0x7FFF + ((v.u >> 16) & 1);
    return (u16)(r >> 16);
}
__device__ __forceinline__ float bf2f(u16 u) {
    union { unsigned u; float f; } v; v.u = ((unsigned)u) << 16; return v.f;
}
// pack two f32 -> one u32 of 2 bf16 (RNE, bit-identical to f2bf pair; pure C, no asm)
__device__ __forceinline__ unsigned pk2bf(float lo, float hi) {
    union { float f; unsigned u; } a, b; a.f = lo; b.f = hi;
    unsigned rl = a.u + 0x7FFFu + ((a.u >> 16) & 1u);
    unsigned rh = b.u + 0x7FFFu + ((b.u >> 16) & 1u);
    return (rh & 0xFFFF0000u) | (rl >> 16);
}

// 16-lane-group reduce via DPP (VALU pipe; replaces ds_bpermute-based __shfl_xor).
__device__ __forceinline__ float dpp_max16(float x) {
    union { float f; int i; } a, b;
    a.f = x; b.i = __builtin_amdgcn_update_dpp(0, a.i, 0xB1, 0xF, 0xF, true); x = fmaxf(x, b.f);
    a.f = x; b.i = __builtin_amdgcn_update_dpp(0, a.i, 0x4E, 0xF, 0xF, true); x = fmaxf(x, b.f);
    a.f = x; b.i = __builtin_amdgcn_update_dpp(0, a.i, 0x124, 0xF, 0xF, true); x = fmaxf(x, b.f);
    a.f = x; b.i = __builtin_amdgcn_update_dpp(0, a.i, 0x128, 0xF, 0xF, true); x = fmaxf(x, b.f);
    return x;
}
__device__ __forceinline__ float dpp_sum16(float x) {
    union { float f; int i; } a, b;
    a.f = x; b.i = __builtin_amdgcn_update_dpp(0, a.i, 0xB1, 0xF, 0xF, true); x += b.f;
    a.f = x; b.i = __builtin_amdgcn_update_dpp(0, a.i, 0x4E, 0xF, 0xF, true); x += b.f;
    a.f = x; b.i = __builtin_amdgcn_update_dpp(0, a.i, 0x124, 0xF, 0xF, true); x += b.f;
    a.f = x; b.i = __builtin_amdgcn_update_dpp(0, a.i, 0x128, 0xF, 0xF, true); x += b.f;
    return x;
}

// async global->LDS DMA, 16 B/lane; dest = wave-uniform base + lane*16
__device__ __forceinline__ void gl_lds16(const void* g, void* s) {
    __builtin_amdgcn_global_load_lds((const __attribute__((address_space(1))) void*)g,
                                     (__attribute__((address_space(3))) void*)s, 16, 0, 0);
}

// ---------------- fused prep: 8 weight transposes + 2 cvts + bias pack, one launch ----------------
struct TJobs {
    const float* src[8];
    u16* dst[8];
    int K[8];
    int N[8];
    int bstart[9];
};

__global__ __launch_bounds__(256) void k_prep(TJobs J, const float* __restrict__ hs, u16* __restrict__ X16,
                                              const float* __restrict__ pos, u16* __restrict__ pos16,
                                              const float* __restrict__ bq, const float* __restrict__ bk,
                                              const float* __restrict__ bv, float* __restrict__ bqkv) {
    __shared__ float tile[32][33];
    int bid = blockIdx.x;
    int T8 = J.bstart[8];
    int tx = threadIdx.x, ty = threadIdx.y;  // (32,8)
    int t = ty * 32 + tx;
    if (bid < T8) {
        // transpose job: f32[K,N] -> bf16[N,K]
        int ji = 0;
        #pragma unroll
        for (int q = 0; q < 8; q++) if (bid >= J.bstart[q + 1]) ji = q + 1;
        const float* W = J.src[ji];
        u16* Wt = J.dst[ji];
        int K = J.K[ji], N = J.N[ji];
        int local = bid - J.bstart[ji];
        int nbx = N >> 5;
        int bx = local % nbx, by = local / nbx;
        int n0 = bx * 32, k0 = by * 32;
        #pragma unroll
        for (int i = 0; i < 32; i += 8)
            tile[ty + i][tx] = W[(size_t)(k0 + ty + i) * N + n0 + tx];
        __syncthreads();
        #pragma unroll
        for (int i = 0; i < 32; i += 8)
            Wt[(size_t)(n0 + ty + i) * K + k0 + tx] = f2bf(tile[tx][ty + i]);
    } else if (bid < T8 + 3072) {
        int i = ((bid - T8) * 256 + t) * 8;   // n = TOK*Hn = 6291456 exactly
        float4 a = *(const float4*)(hs + i);
        float4 b = *(const float4*)(hs + i + 4);
        bf16x8 o;
        o[0] = (short)f2bf(a.x); o[1] = (short)f2bf(a.y); o[2] = (short)f2bf(a.z); o[3] = (short)f2bf(a.w);
        o[4] = (short)f2bf(b.x); o[5] = (short)f2bf(b.y); o[6] = (short)f2bf(b.z); o[7] = (short)f2bf(b.w);
        *(bf16x8*)(X16 + i) = o;
    } else if (bid < T8 + 3456) {
        int i = ((bid - T8 - 3072) * 256 + t) * 8;   // n = 1024*768 = 786432 exactly
        float4 a = *(const float4*)(pos + i);
        float4 b = *(const float4*)(pos + i + 4);
        bf16x8 o;
        o[0] = (short)f2bf(a.x); o[1] = (short)f2bf(a.y); o[2] = (short)f2bf(a.z); o[3] = (short)f2bf(a.w);
        o[4] = (short)f2bf(b.x); o[5] = (short)f2bf(b.y); o[6] = (short)f2bf(b.z); o[7] = (short)f2bf(b.w);
        *(bf16x8*)(pos16 + i) = o;
    } else {
        int i = (bid - T8 - 3456) * 256 + t;
        if (i < 2304) bqkv[i] = (i < 768) ? bq[i] : (i < 1536 ? bk[i - 768] : bv[i - 1536]);
    }
}

// ---------------- bf16 MFMA GEMM: BK=64, global_load_lds, XOR swizzle, XCD-affinity remap ----------------
#define GM_BF16 0
#define GM_F32 1
#define GM_GELU_BF16 2
#define GM_POSH 3   // write bf16 to [h][r][d]: h=col>>6, d=col&63, idx=h*65536+row*64+d

template<int NT>
__global__ __launch_bounds__(256) void k_gemm_t(const u16* __restrict__ A, const u16* __restrict__ Bt,
                                                const float* __restrict__ bias, void* __restrict__ Cout,
                                                int M, int N, int K, int mode) {
    constexpr int TN = NT / 32;
    __shared__ __align__(16) u16 sA[128 * 64];
    __shared__ __align__(16) u16 sB[NT * 64];
    int tid = threadIdx.x;
    int wave = tid >> 6, lane = tid & 63;
    int lane16 = lane & 15, quad = lane >> 4;

    int nb = gridDim.x;
    int flat = blockIdx.y * nb + blockIdx.x;
    int c = flat & 7, g = flat >> 3;
    int mt = c + 8 * (g / nb), nt = g % nb;   // requires gridDim.y % 8 == 0
    int m0 = mt * 128, n0 = nt * NT;

    int wm = (wave >> 1) * 64;
    int wn = (wave & 1) * (NT / 2);
    f32x4 acc[4][TN] = {};

    int r_st = lane >> 3;
    int c8p = lane & 7;

    for (int k0 = 0; k0 < K; k0 += 64) {
        __syncthreads();
        #pragma unroll
        for (int I = 0; I < 4; I++) {
            int Ii = wave + I * 4;
            int r = Ii * 8 + r_st;
            int c8 = c8p ^ (r & 7);
            gl_lds16(&A[(size_t)(m0 + r) * K + k0 + c8 * 8], &sA[Ii * 512]);
        }
        #pragma unroll
        for (int I = 0; I < NT / 32; I++) {
            int Ii = wave + I * 4;
            int r = Ii * 8 + r_st;
            int c8 = c8p ^ (r & 7);
            gl_lds16(&Bt[(size_t)(n0 + r) * K + k0 + c8 * 8], &sB[Ii * 512]);
        }
        __syncthreads();
        #pragma unroll
        for (int h = 0; h < 2; h++) {
            bf16x8 af[4], bfr[TN];
            #pragma unroll
            for (int t = 0; t < 4; t++) {
                int R = wm + t * 16 + lane16;
                af[t] = *(const bf16x8*)&sA[R * 64 + (((4 * h + quad) ^ (R & 7)) << 3)];
            }
            #pragma unroll
            for (int t = 0; t < TN; t++) {
                int R = wn + t * 16 + lane16;
                bfr[t] = *(const bf16x8*)&sB[R * 64 + (((4 * h + quad) ^ (R & 7)) << 3)];
            }
            #pragma unroll
            for (int tm = 0; tm < 4; tm++)
                #pragma unroll
                for (int tn = 0; tn < TN; tn++)
                    acc[tm][tn] = __builtin_amdgcn_mfma_f32_16x16x32_bf16(af[tm], bfr[tn], acc[tm][tn], 0, 0, 0);
        }
    }

    float* Cf = (float*)Cout;
    u16* Ch = (u16*)Cout;
    #pragma unroll
    for (int tm = 0; tm < 4; tm++) {
        #pragma unroll
        for (int tn = 0; tn < TN; tn++) {
            int col = n0 + wn + tn * 16 + lane16;
            float bv_ = bias ? bias[col] : 0.f;
            #pragma unroll
            for (int r = 0; r < 4; r++) {
                int row = m0 + wm + tm * 16 + quad * 4 + r;
                float v = acc[tm][tn][r] + bv_;
                if (mode == GM_GELU_BF16) {
                    v = 0.5f * v * (1.f + erff(v * 0.70710678118654752f));
                    Ch[(size_t)row * N + col] = f2bf(v);
                } else if (mode == GM_BF16) {
                    Ch[(size_t)row * N + col] = f2bf(v);
                } else if (mode == GM_POSH) {
                    Ch[(((size_t)col >> 6) << 16) + ((size_t)row << 6) + (col & 63)] = f2bf(v);
                } else {
                    Cf[(size_t)row * N + col] = v;
                }
            }
        }
    }
}

// ---------------- V transpose: qkv[tok, 1536+h*64+d] -> Vt[(b,h), d, j] ----------------
__global__ __launch_bounds__(256) void k_vt(const u16* __restrict__ qkv, u16* __restrict__ Vt) {
    __shared__ u16 s[64][72];
    int z = blockIdx.y;  // b*12+h
    int j0 = blockIdx.x * 64;
    int b = z / NHn, h = z % NHn;
    int t = threadIdx.x;
    for (int e = t; e < 4096; e += 256) {
        int j = e >> 6, d = e & 63;
        s[j][d] = qkv[(size_t)(b * Sn + j0 + j) * 2304 + 1536 + h * 64 + d];
    }
    __syncthreads();
    for (int e = t; e < 4096; e += 256) {
        int d = e >> 6, jj = e & 63;
        Vt[((size_t)z * 64 + d) * Sn + j0 + jj] = s[jj][d];
    }
}

// ---------------- fused disentangled attention, XCD-affinity with TEMPORAL z-grouping ----------------
// flat = y*8+x; xcd=flat&7; g=flat>>3; z = xcd*24 + (g>>3); i0 = (g&7)*64
// LDS (u16 idx): sK [0,4096) (Q stage at start, P surface later), sV [4096,8192),
// sPK [8192,16384), sPQ [16384,24576); scatter alias s1 [8192,16896), s2 [16896,25600).
//
// R3 HYBRID decomposition + R4 DPP softmax + R7 pk2bf/setprio (verified best: 97.5us).
// R12's GM_QKV V-fusion REVERTED (uncoalesced Vt scatter: 2B stores at 1KB lane
// stride degraded the qkv GEMM 2x; k_vt's LDS transpose restored).
__global__ __launch_bounds__(256, 3) void k_attn(const u16* __restrict__ qkv, const u16* __restrict__ poskR,
                                                 const u16* __restrict__ posqR, const u16* __restrict__ Vt,
                                                 const float* __restrict__ mask, u16* __restrict__ ctx) {
    __shared__ __align__(16) u16 smem[25600];
    u16* sK = smem;
    u16* sV = smem + 4096;
    u16* sPK = smem + 8192;
    u16* s1 = smem + 8192;
    u16* s2 = smem + 16896;

    int flat = blockIdx.y * gridDim.x + blockIdx.x;   // grid (8,192)
    int xcd = flat & 7, g = flat >> 3;                // g in [0,192)
    int z = xcd * 24 + (g >> 3);
    int i0 = (g & 7) * 64;
    int b = z / NHn, h = z % NHn;
    int tid = threadIdx.x, wave = tid >> 6, lane = tid & 63;
    int lane16 = lane & 15, quad = lane >> 4;
    int lr = lane >> 3, lc8 = lane & 7;
    int c8v = (lc8 ^ lr) << 3;   // lane-const swizzled chunk offset (r&7 == lr for all chunks)

    // ---- stage Q once (into sK), read own-wave A-fragments ----
    #pragma unroll
    for (int I = 0; I < 2; I++) {
        int CI = wave * 2 + I;
        int r = CI * 8 + lr;
        gl_lds16(&qkv[(size_t)(b * Sn + i0 + r) * 2304 + h * 64 + c8v], &sK[CI * 512]);
    }
    __syncthreads();
    int Rq = wave * 16 + lane16;
    bf16x8 aqw0 = *(const bf16x8*)&sK[Rq * 64 + (((quad    ) ^ (Rq & 7)) << 3)];
    bf16x8 aqw1 = *(const bf16x8*)&sK[Rq * 64 + (((quad + 4) ^ (Rq & 7)) << 3)];

    // ---- hoisted staging pointers ----
    const u16* kp0 = qkv + (size_t)(b * Sn + wave * 8 + lr) * 2304 + 768 + h * 64 + c8v;
    const u16* kp1 = qkv + (size_t)(b * Sn + (4 + wave) * 8 + lr) * 2304 + 768 + h * 64 + c8v;
    const u16* vp0 = Vt + ((size_t)z * 64 + wave * 8 + lr) * Sn + c8v;
    const u16* vp1 = Vt + ((size_t)z * 64 + (4 + wave) * 8 + lr) * Sn + c8v;
    const u16* pkb = poskR + (size_t)h * 65536 + c8v;
    const u16* pqb = posqR + (size_t)h * 65536 + c8v;
    int rl0 = wave * 8 + lr;   // pos row lane-term for chunk group q: rl0 + 32q

    f32x4 o[4] = {};
    float m_[4] = {-1e30f, -1e30f, -1e30f, -1e30f};
    float l_[4] = {};
    const float scale = 0.07216878364870323f;  // 1/sqrt(3*64)

    for (int jt = 0; jt < 8; jt++) {
        int j0 = jt * 64;
        int r0pk = i0 - j0 + 449, r0pq = j0 - i0 + 449;
        __syncthreads();  // prior iter's P/sV/s1/s2 uses complete before restage
        // ---- stage K(8) V(8) PK(16) PQ(16) 1KB-chunks, 12 DMA per wave ----
        gl_lds16(kp0, &smem[(wave    ) * 512]);  kp0 += 64 * 2304;
        gl_lds16(kp1, &smem[(4 + wave) * 512]);  kp1 += 64 * 2304;
        gl_lds16(vp0, &smem[(8 + wave) * 512]);  vp0 += 64;
        gl_lds16(vp1, &smem[(12 + wave) * 512]); vp1 += 64;
        #pragma unroll
        for (int q = 0; q < 4; q++) {
            int rl = rl0 + 32 * q;
            int rowk = min(r0pk + rl, 1023);
            int rowq = min(r0pq + rl, 1023);
            gl_lds16(pkb + ((size_t)rowk << 6), &smem[(16 + 4 * q + wave) * 512]);
            gl_lds16(pqb + ((size_t)rowq << 6), &smem[(32 + 4 * q + wave) * 512]);
        }
        float mv[4];
        #pragma unroll
        for (int tn = 0; tn < 4; tn++) mv[tn] = mask[(size_t)b * Sn + j0 + tn * 16 + lane16];
        __syncthreads();  // DMA drain + barrier

        // ---- MFMA phase ----
        f32x4 cc[4];
        u32x2 w1h[8], w2h[4][2];
        __builtin_amdgcn_s_setprio(1);
        // cc + p2c (pos-row-partitioned): kf as cc-B and p2c-A, own-band pqf
        {
            bf16x8 pqf0[2], pqf1[2];
            #pragma unroll
            for (int t = 0; t < 2; t++) {
                int R = wave * 32 + t * 16 + lane16;
                pqf0[t] = *(const bf16x8*)&sPK[8192 + R * 64 + (((quad    ) ^ (R & 7)) << 3)];
                pqf1[t] = *(const bf16x8*)&sPK[8192 + R * 64 + (((quad + 4) ^ (R & 7)) << 3)];
            }
            #pragma unroll
            for (int mb = 0; mb < 4; mb++) {
                int R = mb * 16 + lane16;
                bf16x8 kf0 = *(const bf16x8*)&sK[R * 64 + (((quad    ) ^ (R & 7)) << 3)];
                bf16x8 kf1 = *(const bf16x8*)&sK[R * 64 + (((quad + 4) ^ (R & 7)) << 3)];
                f32x4 x = {};
                x = __builtin_amdgcn_mfma_f32_16x16x32_bf16(aqw0, kf0, x, 0, 0, 0);
                x = __builtin_amdgcn_mfma_f32_16x16x32_bf16(aqw1, kf1, x, 0, 0, 0);
                cc[mb] = x;
                #pragma unroll
                for (int t = 0; t < 2; t++) {
                    f32x4 y = {};
                    y = __builtin_amdgcn_mfma_f32_16x16x32_bf16(kf0, pqf0[t], y, 0, 0, 0);
                    y = __builtin_amdgcn_mfma_f32_16x16x32_bf16(kf1, pqf1[t], y, 0, 0, 0);
                    u32x2 pp;
                    pp[0] = pk2bf(y[0], y[1]);
                    pp[1] = pk2bf(y[2], y[3]);
                    w2h[mb][t] = pp;
                }
            }
        }
        // c2p (i-partitioned, R0-style): own aqw x all 8 pos-row-tiles of sPK
        #pragma unroll
        for (int tr = 0; tr < 8; tr++) {
            int R = tr * 16 + lane16;
            bf16x8 b0 = *(const bf16x8*)&sPK[R * 64 + (((quad    ) ^ (R & 7)) << 3)];
            bf16x8 b1 = *(const bf16x8*)&sPK[R * 64 + (((quad + 4) ^ (R & 7)) << 3)];
            f32x4 x = {};
            x = __builtin_amdgcn_mfma_f32_16x16x32_bf16(aqw0, b0, x, 0, 0, 0);
            x = __builtin_amdgcn_mfma_f32_16x16x32_bf16(aqw1, b1, x, 0, 0, 0);
            u32x2 oo;
            oo[0] = pk2bf(x[0], x[1]);
            oo[1] = pk2bf(x[2], x[3]);
            w1h[tr] = oo;
        }
        __builtin_amdgcn_s_setprio(0);
        __syncthreads();  // pos-window reads done; sPK/sPQ become s1/s2

        // ---- diagonal scatter: s1 per-wave COLUMNS (R0), s2 per-wave ROWS (R2) ----
        int sw = wave * 16 + quad * 4;
        #pragma unroll
        for (int tr = 0; tr < 8; tr++)
            *(u32x2*)&s1[(tr * 16 + lane16) * 68 + sw] = w1h[tr];
        #pragma unroll
        for (int mb = 0; mb < 4; mb++)
            #pragma unroll
            for (int t = 0; t < 2; t++) {
                int p = wave * 32 + t * 16 + lane16;
                int ci = mb * 16 + quad * 4;
                *(u32x2*)&s2[p * 68 + ci] = w2h[mb][t];
            }
        __syncthreads();

        // ---- gather + online softmax (DPP reduce) + P write (dead sK, swizzled) + PV ----
        float S[4][4];
        #pragma unroll
        for (int tn = 0; tn < 4; tn++) {
            int jL = tn * 16 + lane16;
            #pragma unroll
            for (int r = 0; r < 4; r++) {
                int iL = wave * 16 + quad * 4 + r;
                float v = cc[tn][r] + bf2f(s1[(iL - jL + 63) * 68 + iL])
                                    + bf2f(s2[(jL - iL + 63) * 68 + jL]);
                v *= scale;
                S[tn][r] = (mv[tn] > 0.f) ? v : -1e9f;
            }
        }
        #pragma unroll
        for (int r = 0; r < 4; r++) {
            float mx = fmaxf(fmaxf(S[0][r], S[1][r]), fmaxf(S[2][r], S[3][r]));
            mx = dpp_max16(mx);
            float mnew = fmaxf(m_[r], mx);
            float alpha = __expf(m_[r] - mnew);
            float p0 = __expf(S[0][r] - mnew), p1 = __expf(S[1][r] - mnew);
            float p2 = __expf(S[2][r] - mnew), p3 = __expf(S[3][r] - mnew);
            float ps = p0 + p1 + p2 + p3;
            ps = dpp_sum16(ps);
            l_[r] = l_[r] * alpha + ps;
            m_[r] = mnew;
            #pragma unroll
            for (int dn = 0; dn < 4; dn++) o[dn][r] *= alpha;
            int prow = wave * 16 + quad * 4 + r;
            int pl = lane16 >> 3, pc = lane16 & 7;
            sK[prow * 64 + (((0 + pl) ^ (prow & 7)) << 3) + pc] = f2bf(p0);
            sK[prow * 64 + (((2 + pl) ^ (prow & 7)) << 3) + pc] = f2bf(p1);
            sK[prow * 64 + (((4 + pl) ^ (prow & 7)) << 3) + pc] = f2bf(p2);
            sK[prow * 64 + (((6 + pl) ^ (prow & 7)) << 3) + pc] = f2bf(p3);
        }
        // PV: A rows are this wave's own rows (same-wave LDS RAW is in-order safe)
        int Rp = wave * 16 + lane16;
        bf16x8 aP0 = *(const bf16x8*)&sK[Rp * 64 + (((quad    ) ^ (Rp & 7)) << 3)];
        bf16x8 aP1 = *(const bf16x8*)&sK[Rp * 64 + (((quad + 4) ^ (Rp & 7)) << 3)];
        __builtin_amdgcn_s_setprio(1);
        #pragma unroll
        for (int dn = 0; dn < 4; dn++) {
            int R = dn * 16 + lane16;
            bf16x8 b0 = *(const bf16x8*)&sV[R * 64 + (((quad    ) ^ (R & 7)) << 3)];
            bf16x8 b1 = *(const bf16x8*)&sV[R * 64 + (((quad + 4) ^ (R & 7)) << 3)];
            o[dn] = __builtin_amdgcn_mfma_f32_16x16x32_bf16(aP0, b0, o[dn], 0, 0, 0);
            o[dn] = __builtin_amdgcn_mfma_f32_16x16x32_bf16(aP1, b1, o[dn], 0, 0, 0);
        }
        __builtin_amdgcn_s_setprio(0);
    }

    // ---- normalize + store ctx ----
    #pragma unroll
    for (int r = 0; r < 4; r++) {
        float inv = 1.f / l_[r];
        int row = i0 + wave * 16 + quad * 4 + r;
        #pragma unroll
        for (int dn = 0; dn < 4; dn++)
            ctx[(size_t)(b * Sn + row) * Hn + h * 64 + dn * 16 + lane16] = f2bf(o[dn][r] * inv);
    }
}

// ---------------- residual + layernorm variants (bf16 tail traffic, R13) ----------------
// LN1: x1 = hs (f32 input), x2 = attnout (bf16), out = h1h (bf16 only; f32 copy dropped)
__global__ __launch_bounds__(256) void k_ln_a(const float* __restrict__ x1, const u16* __restrict__ x2,
                                              const float* __restrict__ g, const float* __restrict__ bb,
                                              u16* __restrict__ outh) {
    int row = blockIdx.x, t = threadIdx.x;
    const float* p1 = x1 + (size_t)row * Hn;
    const u16* p2 = x2 + (size_t)row * Hn;
    float x[3], s1 = 0.f, s2 = 0.f;
    #pragma unroll
    for (int i = 0; i < 3; i++) {
        int c = t + i * 256;
        float v = p1[c] + bf2f(p2[c]);
        x[i] = v; s1 += v; s2 += v * v;
    }
    for (int off = 32; off; off >>= 1) { s1 += __shfl_xor(s1, off); s2 += __shfl_xor(s2, off); }
    __shared__ float a1[4], a2[4];
    if ((t & 63) == 0) { a1[t >> 6] = s1; a2[t >> 6] = s2; }
    __syncthreads();
    s1 = a1[0] + a1[1] + a1[2] + a1[3];
    s2 = a2[0] + a2[1] + a2[2] + a2[3];
    float mu = s1 * (1.f / 768.f);
    float var = s2 * (1.f / 768.f) - mu * mu;
    float rs = rsqrtf(var + 1e-7f);
    #pragma unroll
    for (int i = 0; i < 3; i++) {
        int c = t + i * 256;
        float y = (x[i] - mu) * rs * g[c] + bb[c];
        outh[(size_t)row * Hn + c] = f2bf(y);
    }
}

// LN2: x1 = h1h (bf16 trunk), x2 = ffn2 (bf16), out = final f32
__global__ __launch_bounds__(256) void k_ln_b(const u16* __restrict__ x1, const u16* __restrict__ x2,
                                              const float* __restrict__ g, const float* __restrict__ bb,
                                              float* __restrict__ outf) {
    int row = blockIdx.x, t = threadIdx.x;
    const u16* p1 = x1 + (size_t)row * Hn;
    const u16* p2 = x2 + (size_t)row * Hn;
    float x[3], s1 = 0.f, s2 = 0.f;
    #pragma unroll
    for (int i = 0; i < 3; i++) {
        int c = t + i * 256;
        float v = bf2f(p1[c]) + bf2f(p2[c]);
        x[i] = v; s1 += v; s2 += v * v;
    }
    for (int off = 32; off; off >>= 1) { s1 += __shfl_xor(s1, off); s2 += __shfl_xor(s2, off); }
    __shared__ float a1[4], a2[4];
    if ((t & 63) == 0) { a1[t >> 6] = s1; a2[t >> 6] = s2; }
    __syncthreads();
    s1 = a1[0] + a1[1] + a1[2] + a1[3];
    s2 = a2[0] + a2[1] + a2[2] + a2[3];
    float mu = s1 * (1.f / 768.f);
    float var = s2 * (1.f / 768.f) - mu * mu;
    float rs = rsqrtf(var + 1e-7f);
    #pragma unroll
    for (int i = 0; i < 3; i++) {
        int c = t + i * 256;
        float y = (x[i] - mu) * rs * g[c] + bb[c];
        outf[(size_t)row * Hn + c] = y;
    }
}

extern "C" void kernel_launch(void* const* d_in, const int* in_sizes, int n_in,
                              void* d_out, int out_size, void* d_ws, size_t ws_size,
                              hipStream_t stream) {
    const float* hs   = (const float*)d_in[0];
    const float* mask = (const float*)d_in[1];
    const float* pos  = (const float*)d_in[2];
    const float* Wq = (const float*)d_in[3],  *bq = (const float*)d_in[4];
    const float* Wk = (const float*)d_in[5],  *bk = (const float*)d_in[6];
    const float* Wv = (const float*)d_in[7],  *bv = (const float*)d_in[8];
    const float* Wpk = (const float*)d_in[9], *Wpq = (const float*)d_in[10];
    const float* Wo = (const float*)d_in[11], *bo = (const float*)d_in[12];
    const float* g1 = (const float*)d_in[13], *b1ln = (const float*)d_in[14];
    const float* W1 = (const float*)d_in[15], *b1f = (const float*)d_in[16];
    const float* W2 = (const float*)d_in[17], *b2f = (const float*)d_in[18];
    const float* g2 = (const float*)d_in[19], *b2ln = (const float*)d_in[20];
    float* out = (float*)d_out;

    char* w = (char*)d_ws;
    u16*  X16    = (u16*)w;                 w += 12582912;   // [8192,768] bf16
    u16*  pos16  = (u16*)w;                 w += 1572864;    // [1024,768] bf16
    u16*  WqkvT  = (u16*)w;                 w += 3538944;    // [2304,768] bf16
    float* bqkv  = (float*)w;               w += 9216;       // [2304]
    u16*  WoT    = (u16*)w;                 w += 1179648;    // [768,768]
    u16*  W1T    = (u16*)w;                 w += 4718592;    // [3072,768]
    u16*  W2T    = (u16*)w;                 w += 4718592;    // [768,3072]
    u16*  WpkT   = (u16*)w;                 w += 1179648;
    u16*  WpqT   = (u16*)w;                 w += 1179648;    // adjacent to WpkT (merged pos GEMM)
    u16*  posk   = (u16*)w;                 w += 1572864;    // [12][1024][64] bf16 per-head
    u16*  posq   = (u16*)w;                 w += 1572864;    // adjacent to posk (GM_POSH spans both)
    u16*  qkv    = (u16*)w;                 w += 37748736;   // [8192,2304] bf16 (read-only during attn)
    u16*  Vt     = (u16*)w;                 w += 12582912;   // [192,64,512] bf16
    char* big    = w;                       w += 100663296;
    u16*  att16  = (u16*)w;                 w += 12582912;   // [8192,768] bf16 (Wo out; later ffn2 out)
    // lifetime-disjoint carve-up of `big`:
    u16*  ctx  = (u16*)big;                        // [0, 12.6MB)  written by k_attn
    u16*  ffn1 = (u16*)(big + 50331648);           // [48MB, 98.6MB)
    u16*  h1h  = X16;                              // X16 dead after qkv GEMM
    u16*  ffn2 = att16;                            // att16 dead after LN1

    // prep: fused converts + weight transposes + bias pack (one launch)
    TJobs J;
    J.src[0] = Wq;  J.dst[0] = WqkvT;           J.K[0] = 768;  J.N[0] = 768;
    J.src[1] = Wk;  J.dst[1] = WqkvT + 589824;  J.K[1] = 768;  J.N[1] = 768;
    J.src[2] = Wv;  J.dst[2] = WqkvT + 1179648; J.K[2] = 768;  J.N[2] = 768;
    J.src[3] = Wo;  J.dst[3] = WoT;             J.K[3] = 768;  J.N[3] = 768;
    J.src[4] = Wpk; J.dst[4] = WpkT;            J.K[4] = 768;  J.N[4] = 768;
    J.src[5] = Wpq; J.dst[5] = WpqT;            J.K[5] = 768;  J.N[5] = 768;
    J.src[6] = W1;  J.dst[6] = W1T;             J.K[6] = 768;  J.N[6] = 3072;
    J.src[7] = W2;  J.dst[7] = W2T;             J.K[7] = 3072; J.N[7] = 768;
    J.bstart[0] = 0;
    for (int i = 0; i < 8; i++) J.bstart[i + 1] = J.bstart[i] + (J.N[i] >> 5) * (J.K[i] >> 5);
    k_prep<<<J.bstart[8] + 3465, dim3(32, 8), 0, stream>>>(J, hs, X16, pos, pos16, bq, bk, bv, bqkv);

    // projections (merged pos GEMM: N=1536 spans WpkT||WpqT -> posk||posq via GM_POSH)
    k_gemm_t<128><<<dim3(18, 64), 256, 0, stream>>>(X16, WqkvT, bqkv, qkv, TOK, 2304, 768, GM_BF16);
    k_gemm_t<128><<<dim3(12, 8), 256, 0, stream>>>(pos16, WpkT, nullptr, posk, 1024, 1536, 768, GM_POSH);

    // fused attention
    k_vt<<<dim3(8, 192), 256, 0, stream>>>(qkv, Vt);
    k_attn<<<dim3(8, 192), 256, 0, stream>>>(qkv, posk, posq, Vt, mask, ctx);
    k_gemm_t<64><<<dim3(12, 64), 256, 0, stream>>>(ctx, WoT, bo, att16, TOK, 768, 768, GM_BF16);
    k_ln_a<<<TOK, 256, 0, stream>>>(hs, att16, g1, b1ln, h1h);

    // FFN (bf16 tail: ffn2 out bf16, LN2 reads bf16 trunk + bf16 ffn2)
    k_gemm_t<128><<<dim3(24, 64), 256, 0, stream>>>(h1h, W1T, b1f, ffn1, TOK, 3072, 768, GM_GELU_BF16);
    k_gemm_t<64><<<dim3(12, 64), 256, 0, stream>>>(ffn1, W2T, b2f, ffn2, TOK, 768, 3072, GM_BF16);
    k_ln_b<<<TOK, 256, 0, stream>>>(h1h, ffn2, g2, b2ln, out);
}

// Round 16
// 456.665 us; speedup vs baseline: 1.2756x; 1.0393x over previous
//
#include <hip/hip_runtime.h>
#include <math.h>

#define Bn 16
#define Sn 512
#define Hn 768
#define NHn 12
#define DHn 64
#define In 3072
#define TOK (Bn*Sn)

typedef unsigned short u16;
typedef short bf16x8 __attribute__((ext_vector_type(8)));
typedef short bf16x4 __attribute__((ext_vector_type(4)));
typedef float f32x4 __attribute__((ext_vector_type(4)));
typedef unsigned int u32x2 __attribute__((ext_vector_type(2)));

__device__ __forceinline__ u16 f2bf(float x) {
    union { float f; unsigned u; } v; v.f = x;
    unsigned r = v.u + 0x7FFF + ((v.u >> 16) & 1);
    return (u16)(r >> 16);
}
__device__ __forceinline__ float bf2f(u16 u) {
    union { unsigned u; float f; } v; v.u = ((unsigned)u) << 16; return v.f;
}
// pack two f32 -> one u32 of 2 bf16 (RNE, bit-identical to f2bf pair; pure C, no asm)
__device__ __forceinline__ unsigned pk2bf(float lo, float hi) {
    union { float f; unsigned u; } a, b; a.f = lo; b.f = hi;
    unsigned rl = a.u + 0x7FFFu + ((a.u >> 16) & 1u);
    unsigned rh = b.u + 0x7FFFu + ((b.u >> 16) & 1u);
    return (rh & 0xFFFF0000u) | (rl >> 16);
}

// 16-lane-group reduce via DPP (VALU pipe; replaces ds_bpermute-based __shfl_xor).
__device__ __forceinline__ float dpp_max16(float x) {
    union { float f; int i; } a, b;
    a.f = x; b.i = __builtin_amdgcn_update_dpp(0, a.i, 0xB1, 0xF, 0xF, true); x = fmaxf(x, b.f);
    a.f = x; b.i = __builtin_amdgcn_update_dpp(0, a.i, 0x4E, 0xF, 0xF, true); x = fmaxf(x, b.f);
    a.f = x; b.i = __builtin_amdgcn_update_dpp(0, a.i, 0x124, 0xF, 0xF, true); x = fmaxf(x, b.f);
    a.f = x; b.i = __builtin_amdgcn_update_dpp(0, a.i, 0x128, 0xF, 0xF, true); x = fmaxf(x, b.f);
    return x;
}
__device__ __forceinline__ float dpp_sum16(float x) {
    union { float f; int i; } a, b;
    a.f = x; b.i = __builtin_amdgcn_update_dpp(0, a.i, 0xB1, 0xF, 0xF, true); x += b.f;
    a.f = x; b.i = __builtin_amdgcn_update_dpp(0, a.i, 0x4E, 0xF, 0xF, true); x += b.f;
    a.f = x; b.i = __builtin_amdgcn_update_dpp(0, a.i, 0x124, 0xF, 0xF, true); x += b.f;
    a.f = x; b.i = __builtin_amdgcn_update_dpp(0, a.i, 0x128, 0xF, 0xF, true); x += b.f;
    return x;
}

// async global->LDS DMA, 16 B/lane; dest = wave-uniform base + lane*16
__device__ __forceinline__ void gl_lds16(const void* g, void* s) {
    __builtin_amdgcn_global_load_lds((const __attribute__((address_space(1))) void*)g,
                                     (__attribute__((address_space(3))) void*)s, 16, 0, 0);
}

// ---------------- fused prep: 8 weight transposes + 2 cvts + bias pack, one launch ----------------
struct TJobs {
    const float* src[8];
    u16* dst[8];
    int K[8];
    int N[8];
    int bstart[9];
};

__global__ __launch_bounds__(256) void k_prep(TJobs J, const float* __restrict__ hs, u16* __restrict__ X16,
                                              const float* __restrict__ pos, u16* __restrict__ pos16,
                                              const float* __restrict__ bq, const float* __restrict__ bk,
                                              const float* __restrict__ bv, float* __restrict__ bqkv) {
    __shared__ float tile[32][33];
    int bid = blockIdx.x;
    int T8 = J.bstart[8];
    int tx = threadIdx.x, ty = threadIdx.y;  // (32,8)
    int t = ty * 32 + tx;
    if (bid < T8) {
        // transpose job: f32[K,N] -> bf16[N,K]
        int ji = 0;
        #pragma unroll
        for (int q = 0; q < 8; q++) if (bid >= J.bstart[q + 1]) ji = q + 1;
        const float* W = J.src[ji];
        u16* Wt = J.dst[ji];
        int K = J.K[ji], N = J.N[ji];
        int local = bid - J.bstart[ji];
        int nbx = N >> 5;
        int bx = local % nbx, by = local / nbx;
        int n0 = bx * 32, k0 = by * 32;
        #pragma unroll
        for (int i = 0; i < 32; i += 8)
            tile[ty + i][tx] = W[(size_t)(k0 + ty + i) * N + n0 + tx];
        __syncthreads();
        #pragma unroll
        for (int i = 0; i < 32; i += 8)
            Wt[(size_t)(n0 + ty + i) * K + k0 + tx] = f2bf(tile[tx][ty + i]);
    } else if (bid < T8 + 3072) {
        int i = ((bid - T8) * 256 + t) * 8;   // n = TOK*Hn = 6291456 exactly
        float4 a = *(const float4*)(hs + i);
        float4 b = *(const float4*)(hs + i + 4);
        bf16x8 o;
        o[0] = (short)f2bf(a.x); o[1] = (short)f2bf(a.y); o[2] = (short)f2bf(a.z); o[3] = (short)f2bf(a.w);
        o[4] = (short)f2bf(b.x); o[5] = (short)f2bf(b.y); o[6] = (short)f2bf(b.z); o[7] = (short)f2bf(b.w);
        *(bf16x8*)(X16 + i) = o;
    } else if (bid < T8 + 3456) {
        int i = ((bid - T8 - 3072) * 256 + t) * 8;   // n = 1024*768 = 786432 exactly
        float4 a = *(const float4*)(pos + i);
        float4 b = *(const float4*)(pos + i + 4);
        bf16x8 o;
        o[0] = (short)f2bf(a.x); o[1] = (short)f2bf(a.y); o[2] = (short)f2bf(a.z); o[3] = (short)f2bf(a.w);
        o[4] = (short)f2bf(b.x); o[5] = (short)f2bf(b.y); o[6] = (short)f2bf(b.z); o[7] = (short)f2bf(b.w);
        *(bf16x8*)(pos16 + i) = o;
    } else {
        int i = (bid - T8 - 3456) * 256 + t;
        if (i < 2304) bqkv[i] = (i < 768) ? bq[i] : (i < 1536 ? bk[i - 768] : bv[i - 1536]);
    }
}

// ---------------- bf16 MFMA GEMM body: BK=64, global_load_lds, XOR swizzle, XCD-affinity remap ----------------
#define GM_BF16 0
#define GM_F32 1
#define GM_GELU_BF16 2
#define GM_POSH 3   // write bf16 to [h][r][d]: h=col>>6, d=col&63, idx=h*65536+row*64+d

template<int NT>
__device__ __forceinline__ void gemm_body(int flat, int nb,
                                          const u16* __restrict__ A, const u16* __restrict__ Bt,
                                          const float* __restrict__ bias, void* __restrict__ Cout,
                                          int M, int N, int K, int mode,
                                          u16* sA, u16* sB) {
    constexpr int TN = NT / 32;
    int tid = threadIdx.x;
    int wave = tid >> 6, lane = tid & 63;
    int lane16 = lane & 15, quad = lane >> 4;

    int c = flat & 7, g = flat >> 3;
    int mt = c + 8 * (g / nb), nt = g % nb;   // requires total blocks % 8 == 0 per job
    int m0 = mt * 128, n0 = nt * NT;

    int wm = (wave >> 1) * 64;
    int wn = (wave & 1) * (NT / 2);
    f32x4 acc[4][TN] = {};

    int r_st = lane >> 3;
    int c8p = lane & 7;

    for (int k0 = 0; k0 < K; k0 += 64) {
        __syncthreads();
        #pragma unroll
        for (int I = 0; I < 4; I++) {
            int Ii = wave + I * 4;
            int r = Ii * 8 + r_st;
            int c8 = c8p ^ (r & 7);
            gl_lds16(&A[(size_t)(m0 + r) * K + k0 + c8 * 8], &sA[Ii * 512]);
        }
        #pragma unroll
        for (int I = 0; I < NT / 32; I++) {
            int Ii = wave + I * 4;
            int r = Ii * 8 + r_st;
            int c8 = c8p ^ (r & 7);
            gl_lds16(&Bt[(size_t)(n0 + r) * K + k0 + c8 * 8], &sB[Ii * 512]);
        }
        __syncthreads();
        #pragma unroll
        for (int h = 0; h < 2; h++) {
            bf16x8 af[4], bfr[TN];
            #pragma unroll
            for (int t = 0; t < 4; t++) {
                int R = wm + t * 16 + lane16;
                af[t] = *(const bf16x8*)&sA[R * 64 + (((4 * h + quad) ^ (R & 7)) << 3)];
            }
            #pragma unroll
            for (int t = 0; t < TN; t++) {
                int R = wn + t * 16 + lane16;
                bfr[t] = *(const bf16x8*)&sB[R * 64 + (((4 * h + quad) ^ (R & 7)) << 3)];
            }
            #pragma unroll
            for (int tm = 0; tm < 4; tm++)
                #pragma unroll
                for (int tn = 0; tn < TN; tn++)
                    acc[tm][tn] = __builtin_amdgcn_mfma_f32_16x16x32_bf16(af[tm], bfr[tn], acc[tm][tn], 0, 0, 0);
        }
    }

    float* Cf = (float*)Cout;
    u16* Ch = (u16*)Cout;
    #pragma unroll
    for (int tm = 0; tm < 4; tm++) {
        #pragma unroll
        for (int tn = 0; tn < TN; tn++) {
            int col = n0 + wn + tn * 16 + lane16;
            float bv_ = bias ? bias[col] : 0.f;
            #pragma unroll
            for (int r = 0; r < 4; r++) {
                int row = m0 + wm + tm * 16 + quad * 4 + r;
                float v = acc[tm][tn][r] + bv_;
                if (mode == GM_GELU_BF16) {
                    v = 0.5f * v * (1.f + erff(v * 0.70710678118654752f));
                    Ch[(size_t)row * N + col] = f2bf(v);
                } else if (mode == GM_BF16) {
                    Ch[(size_t)row * N + col] = f2bf(v);
                } else if (mode == GM_POSH) {
                    Ch[(((size_t)col >> 6) << 16) + ((size_t)row << 6) + (col & 63)] = f2bf(v);
                } else {
                    Cf[(size_t)row * N + col] = v;
                }
            }
        }
    }
}

template<int NT>
__global__ __launch_bounds__(256) void k_gemm_t(const u16* __restrict__ A, const u16* __restrict__ Bt,
                                                const float* __restrict__ bias, void* __restrict__ Cout,
                                                int M, int N, int K, int mode) {
    __shared__ __align__(16) u16 sA[128 * 64];
    __shared__ __align__(16) u16 sB[NT * 64];
    int flat = blockIdx.y * gridDim.x + blockIdx.x;
    gemm_body<NT>(flat, gridDim.x, A, Bt, bias, Cout, M, N, K, mode, sA, sB);
}

// merged projections: blocks [0,1152) = qkv GEMM (nb=18), [1152,1248) = pos GEMM (nb=12).
// pos blocks fill the qkv GEMM's half-empty tail dispatch round; one launch gap removed.
__global__ __launch_bounds__(256) void k_gemm_proj(const u16* __restrict__ X16, const u16* __restrict__ WqkvT,
                                                   const float* __restrict__ bqkv, u16* __restrict__ qkv,
                                                   const u16* __restrict__ pos16, const u16* __restrict__ WpkT,
                                                   u16* __restrict__ posk) {
    __shared__ __align__(16) u16 sA[128 * 64];
    __shared__ __align__(16) u16 sB[128 * 64];
    int bid = blockIdx.x;
    if (bid < 1152) {
        gemm_body<128>(bid, 18, X16, WqkvT, bqkv, (void*)qkv, TOK, 2304, 768, GM_BF16, sA, sB);
    } else {
        gemm_body<128>(bid - 1152, 12, pos16, WpkT, nullptr, (void*)posk, 1024, 1536, 768, GM_POSH, sA, sB);
    }
}

// ---------------- V transpose: qkv[tok, 1536+h*64+d] -> Vt[(b,h), d, j] ----------------
__global__ __launch_bounds__(256) void k_vt(const u16* __restrict__ qkv, u16* __restrict__ Vt) {
    __shared__ u16 s[64][72];
    int z = blockIdx.y;  // b*12+h
    int j0 = blockIdx.x * 64;
    int b = z / NHn, h = z % NHn;
    int t = threadIdx.x;
    for (int e = t; e < 4096; e += 256) {
        int j = e >> 6, d = e & 63;
        s[j][d] = qkv[(size_t)(b * Sn + j0 + j) * 2304 + 1536 + h * 64 + d];
    }
    __syncthreads();
    for (int e = t; e < 4096; e += 256) {
        int d = e >> 6, jj = e & 63;
        Vt[((size_t)z * 64 + d) * Sn + j0 + jj] = s[jj][d];
    }
}

// ---------------- fused disentangled attention, XCD-affinity with TEMPORAL z-grouping ----------------
// flat = y*8+x; xcd=flat&7; g=flat>>3; z = xcd*24 + (g>>3); i0 = (g&7)*64
// LDS (u16 idx): sK [0,4096) (Q stage at start, P surface later), sV [4096,8192),
// sPK [8192,16384), sPQ [16384,24576); scatter alias s1 [8192,16896), s2 [16896,25600).
//
// R3 HYBRID decomposition + R4 DPP softmax + R7 pk2bf/setprio (verified best: 97.5us).
__global__ __launch_bounds__(256, 3) void k_attn(const u16* __restrict__ qkv, const u16* __restrict__ poskR,
                                                 const u16* __restrict__ posqR, const u16* __restrict__ Vt,
                                                 const float* __restrict__ mask, u16* __restrict__ ctx) {
    __shared__ __align__(16) u16 smem[25600];
    u16* sK = smem;
    u16* sV = smem + 4096;
    u16* sPK = smem + 8192;
    u16* s1 = smem + 8192;
    u16* s2 = smem + 16896;

    int flat = blockIdx.y * gridDim.x + blockIdx.x;   // grid (8,192)
    int xcd = flat & 7, g = flat >> 3;                // g in [0,192)
    int z = xcd * 24 + (g >> 3);
    int i0 = (g & 7) * 64;
    int b = z / NHn, h = z % NHn;
    int tid = threadIdx.x, wave = tid >> 6, lane = tid & 63;
    int lane16 = lane & 15, quad = lane >> 4;
    int lr = lane >> 3, lc8 = lane & 7;
    int c8v = (lc8 ^ lr) << 3;   // lane-const swizzled chunk offset (r&7 == lr for all chunks)

    // ---- stage Q once (into sK), read own-wave A-fragments ----
    #pragma unroll
    for (int I = 0; I < 2; I++) {
        int CI = wave * 2 + I;
        int r = CI * 8 + lr;
        gl_lds16(&qkv[(size_t)(b * Sn + i0 + r) * 2304 + h * 64 + c8v], &sK[CI * 512]);
    }
    __syncthreads();
    int Rq = wave * 16 + lane16;
    bf16x8 aqw0 = *(const bf16x8*)&sK[Rq * 64 + (((quad    ) ^ (Rq & 7)) << 3)];
    bf16x8 aqw1 = *(const bf16x8*)&sK[Rq * 64 + (((quad + 4) ^ (Rq & 7)) << 3)];

    // ---- hoisted staging pointers ----
    const u16* kp0 = qkv + (size_t)(b * Sn + wave * 8 + lr) * 2304 + 768 + h * 64 + c8v;
    const u16* kp1 = qkv + (size_t)(b * Sn + (4 + wave) * 8 + lr) * 2304 + 768 + h * 64 + c8v;
    const u16* vp0 = Vt + ((size_t)z * 64 + wave * 8 + lr) * Sn + c8v;
    const u16* vp1 = Vt + ((size_t)z * 64 + (4 + wave) * 8 + lr) * Sn + c8v;
    const u16* pkb = poskR + (size_t)h * 65536 + c8v;
    const u16* pqb = posqR + (size_t)h * 65536 + c8v;
    int rl0 = wave * 8 + lr;   // pos row lane-term for chunk group q: rl0 + 32q

    f32x4 o[4] = {};
    float m_[4] = {-1e30f, -1e30f, -1e30f, -1e30f};
    float l_[4] = {};
    const float scale = 0.07216878364870323f;  // 1/sqrt(3*64)

    for (int jt = 0; jt < 8; jt++) {
        int j0 = jt * 64;
        int r0pk = i0 - j0 + 449, r0pq = j0 - i0 + 449;
        __syncthreads();  // prior iter's P/sV/s1/s2 uses complete before restage
        // ---- stage K(8) V(8) PK(16) PQ(16) 1KB-chunks, 12 DMA per wave ----
        gl_lds16(kp0, &smem[(wave    ) * 512]);  kp0 += 64 * 2304;
        gl_lds16(kp1, &smem[(4 + wave) * 512]);  kp1 += 64 * 2304;
        gl_lds16(vp0, &smem[(8 + wave) * 512]);  vp0 += 64;
        gl_lds16(vp1, &smem[(12 + wave) * 512]); vp1 += 64;
        #pragma unroll
        for (int q = 0; q < 4; q++) {
            int rl = rl0 + 32 * q;
            int rowk = min(r0pk + rl, 1023);
            int rowq = min(r0pq + rl, 1023);
            gl_lds16(pkb + ((size_t)rowk << 6), &smem[(16 + 4 * q + wave) * 512]);
            gl_lds16(pqb + ((size_t)rowq << 6), &smem[(32 + 4 * q + wave) * 512]);
        }
        float mv[4];
        #pragma unroll
        for (int tn = 0; tn < 4; tn++) mv[tn] = mask[(size_t)b * Sn + j0 + tn * 16 + lane16];
        __syncthreads();  // DMA drain + barrier

        // ---- MFMA phase ----
        f32x4 cc[4];
        u32x2 w1h[8], w2h[4][2];
        __builtin_amdgcn_s_setprio(1);
        // cc + p2c (pos-row-partitioned): kf as cc-B and p2c-A, own-band pqf
        {
            bf16x8 pqf0[2], pqf1[2];
            #pragma unroll
            for (int t = 0; t < 2; t++) {
                int R = wave * 32 + t * 16 + lane16;
                pqf0[t] = *(const bf16x8*)&sPK[8192 + R * 64 + (((quad    ) ^ (R & 7)) << 3)];
                pqf1[t] = *(const bf16x8*)&sPK[8192 + R * 64 + (((quad + 4) ^ (R & 7)) << 3)];
            }
            #pragma unroll
            for (int mb = 0; mb < 4; mb++) {
                int R = mb * 16 + lane16;
                bf16x8 kf0 = *(const bf16x8*)&sK[R * 64 + (((quad    ) ^ (R & 7)) << 3)];
                bf16x8 kf1 = *(const bf16x8*)&sK[R * 64 + (((quad + 4) ^ (R & 7)) << 3)];
                f32x4 x = {};
                x = __builtin_amdgcn_mfma_f32_16x16x32_bf16(aqw0, kf0, x, 0, 0, 0);
                x = __builtin_amdgcn_mfma_f32_16x16x32_bf16(aqw1, kf1, x, 0, 0, 0);
                cc[mb] = x;
                #pragma unroll
                for (int t = 0; t < 2; t++) {
                    f32x4 y = {};
                    y = __builtin_amdgcn_mfma_f32_16x16x32_bf16(kf0, pqf0[t], y, 0, 0, 0);
                    y = __builtin_amdgcn_mfma_f32_16x16x32_bf16(kf1, pqf1[t], y, 0, 0, 0);
                    u32x2 pp;
                    pp[0] = pk2bf(y[0], y[1]);
                    pp[1] = pk2bf(y[2], y[3]);
                    w2h[mb][t] = pp;
                }
            }
        }
        // c2p (i-partitioned, R0-style): own aqw x all 8 pos-row-tiles of sPK
        #pragma unroll
        for (int tr = 0; tr < 8; tr++) {
            int R = tr * 16 + lane16;
            bf16x8 b0 = *(const bf16x8*)&sPK[R * 64 + (((quad    ) ^ (R & 7)) << 3)];
            bf16x8 b1 = *(const bf16x8*)&sPK[R * 64 + (((quad + 4) ^ (R & 7)) << 3)];
            f32x4 x = {};
            x = __builtin_amdgcn_mfma_f32_16x16x32_bf16(aqw0, b0, x, 0, 0, 0);
            x = __builtin_amdgcn_mfma_f32_16x16x32_bf16(aqw1, b1, x, 0, 0, 0);
            u32x2 oo;
            oo[0] = pk2bf(x[0], x[1]);
            oo[1] = pk2bf(x[2], x[3]);
            w1h[tr] = oo;
        }
        __builtin_amdgcn_s_setprio(0);
        __syncthreads();  // pos-window reads done; sPK/sPQ become s1/s2

        // ---- diagonal scatter: s1 per-wave COLUMNS (R0), s2 per-wave ROWS (R2) ----
        int sw = wave * 16 + quad * 4;
        #pragma unroll
        for (int tr = 0; tr < 8; tr++)
            *(u32x2*)&s1[(tr * 16 + lane16) * 68 + sw] = w1h[tr];
        #pragma unroll
        for (int mb = 0; mb < 4; mb++)
            #pragma unroll
            for (int t = 0; t < 2; t++) {
                int p = wave * 32 + t * 16 + lane16;
                int ci = mb * 16 + quad * 4;
                *(u32x2*)&s2[p * 68 + ci] = w2h[mb][t];
            }
        __syncthreads();

        // ---- gather + online softmax (DPP reduce) + P write (dead sK, swizzled) + PV ----
        float S[4][4];
        #pragma unroll
        for (int tn = 0; tn < 4; tn++) {
            int jL = tn * 16 + lane16;
            #pragma unroll
            for (int r = 0; r < 4; r++) {
                int iL = wave * 16 + quad * 4 + r;
                float v = cc[tn][r] + bf2f(s1[(iL - jL + 63) * 68 + iL])
                                    + bf2f(s2[(jL - iL + 63) * 68 + jL]);
                v *= scale;
                S[tn][r] = (mv[tn] > 0.f) ? v : -1e9f;
            }
        }
        #pragma unroll
        for (int r = 0; r < 4; r++) {
            float mx = fmaxf(fmaxf(S[0][r], S[1][r]), fmaxf(S[2][r], S[3][r]));
            mx = dpp_max16(mx);
            float mnew = fmaxf(m_[r], mx);
            float alpha = __expf(m_[r] - mnew);
            float p0 = __expf(S[0][r] - mnew), p1 = __expf(S[1][r] - mnew);
            float p2 = __expf(S[2][r] - mnew), p3 = __expf(S[3][r] - mnew);
            float ps = p0 + p1 + p2 + p3;
            ps = dpp_sum16(ps);
            l_[r] = l_[r] * alpha + ps;
            m_[r] = mnew;
            #pragma unroll
            for (int dn = 0; dn < 4; dn++) o[dn][r] *= alpha;
            int prow = wave * 16 + quad * 4 + r;
            int pl = lane16 >> 3, pc = lane16 & 7;
            sK[prow * 64 + (((0 + pl) ^ (prow & 7)) << 3) + pc] = f2bf(p0);
            sK[prow * 64 + (((2 + pl) ^ (prow & 7)) << 3) + pc] = f2bf(p1);
            sK[prow * 64 + (((4 + pl) ^ (prow & 7)) << 3) + pc] = f2bf(p2);
            sK[prow * 64 + (((6 + pl) ^ (prow & 7)) << 3) + pc] = f2bf(p3);
        }
        // PV: A rows are this wave's own rows (same-wave LDS RAW is in-order safe)
        int Rp = wave * 16 + lane16;
        bf16x8 aP0 = *(const bf16x8*)&sK[Rp * 64 + (((quad    ) ^ (Rp & 7)) << 3)];
        bf16x8 aP1 = *(const bf16x8*)&sK[Rp * 64 + (((quad + 4) ^ (Rp & 7)) << 3)];
        __builtin_amdgcn_s_setprio(1);
        #pragma unroll
        for (int dn = 0; dn < 4; dn++) {
            int R = dn * 16 + lane16;
            bf16x8 b0 = *(const bf16x8*)&sV[R * 64 + (((quad    ) ^ (R & 7)) << 3)];
            bf16x8 b1 = *(const bf16x8*)&sV[R * 64 + (((quad + 4) ^ (R & 7)) << 3)];
            o[dn] = __builtin_amdgcn_mfma_f32_16x16x32_bf16(aP0, b0, o[dn], 0, 0, 0);
            o[dn] = __builtin_amdgcn_mfma_f32_16x16x32_bf16(aP1, b1, o[dn], 0, 0, 0);
        }
        __builtin_amdgcn_s_setprio(0);
    }

    // ---- normalize + store ctx ----
    #pragma unroll
    for (int r = 0; r < 4; r++) {
        float inv = 1.f / l_[r];
        int row = i0 + wave * 16 + quad * 4 + r;
        #pragma unroll
        for (int dn = 0; dn < 4; dn++)
            ctx[(size_t)(b * Sn + row) * Hn + h * 64 + dn * 16 + lane16] = f2bf(o[dn][r] * inv);
    }
}

// ---------------- residual + layernorm variants (bf16 tail traffic, R13-verified) ----------------
// LN1: x1 = hs (f32 input), x2 = attnout (bf16), out = h1h (bf16 only)
__global__ __launch_bounds__(256) void k_ln_a(const float* __restrict__ x1, const u16* __restrict__ x2,
                                              const float* __restrict__ g, const float* __restrict__ bb,
                                              u16* __restrict__ outh) {
    int row = blockIdx.x, t = threadIdx.x;
    const float* p1 = x1 + (size_t)row * Hn;
    const u16* p2 = x2 + (size_t)row * Hn;
    float x[3], s1 = 0.f, s2 = 0.f;
    #pragma unroll
    for (int i = 0; i < 3; i++) {
        int c = t + i * 256;
        float v = p1[c] + bf2f(p2[c]);
        x[i] = v; s1 += v; s2 += v * v;
    }
    for (int off = 32; off; off >>= 1) { s1 += __shfl_xor(s1, off); s2 += __shfl_xor(s2, off); }
    __shared__ float a1[4], a2[4];
    if ((t & 63) == 0) { a1[t >> 6] = s1; a2[t >> 6] = s2; }
    __syncthreads();
    s1 = a1[0] + a1[1] + a1[2] + a1[3];
    s2 = a2[0] + a2[1] + a2[2] + a2[3];
    float mu = s1 * (1.f / 768.f);
    float var = s2 * (1.f / 768.f) - mu * mu;
    float rs = rsqrtf(var + 1e-7f);
    #pragma unroll
    for (int i = 0; i < 3; i++) {
        int c = t + i * 256;
        float y = (x[i] - mu) * rs * g[c] + bb[c];
        outh[(size_t)row * Hn + c] = f2bf(y);
    }
}

// LN2: x1 = h1h (bf16 trunk), x2 = ffn2 (bf16), out = final f32
__global__ __launch_bounds__(256) void k_ln_b(const u16* __restrict__ x1, const u16* __restrict__ x2,
                                              const float* __restrict__ g, const float* __restrict__ bb,
                                              float* __restrict__ outf) {
    int row = blockIdx.x, t = threadIdx.x;
    const u16* p1 = x1 + (size_t)row * Hn;
    const u16* p2 = x2 + (size_t)row * Hn;
    float x[3], s1 = 0.f, s2 = 0.f;
    #pragma unroll
    for (int i = 0; i < 3; i++) {
        int c = t + i * 256;
        float v = bf2f(p1[c]) + bf2f(p2[c]);
        x[i] = v; s1 += v; s2 += v * v;
    }
    for (int off = 32; off; off >>= 1) { s1 += __shfl_xor(s1, off); s2 += __shfl_xor(s2, off); }
    __shared__ float a1[4], a2[4];
    if ((t & 63) == 0) { a1[t >> 6] = s1; a2[t >> 6] = s2; }
    __syncthreads();
    s1 = a1[0] + a1[1] + a1[2] + a1[3];
    s2 = a2[0] + a2[1] + a2[2] + a2[3];
    float mu = s1 * (1.f / 768.f);
    float var = s2 * (1.f / 768.f) - mu * mu;
    float rs = rsqrtf(var + 1e-7f);
    #pragma unroll
    for (int i = 0; i < 3; i++) {
        int c = t + i * 256;
        float y = (x[i] - mu) * rs * g[c] + bb[c];
        outf[(size_t)row * Hn + c] = y;
    }
}

extern "C" void kernel_launch(void* const* d_in, const int* in_sizes, int n_in,
                              void* d_out, int out_size, void* d_ws, size_t ws_size,
                              hipStream_t stream) {
    const float* hs   = (const float*)d_in[0];
    const float* mask = (const float*)d_in[1];
    const float* pos  = (const float*)d_in[2];
    const float* Wq = (const float*)d_in[3],  *bq = (const float*)d_in[4];
    const float* Wk = (const float*)d_in[5],  *bk = (const float*)d_in[6];
    const float* Wv = (const float*)d_in[7],  *bv = (const float*)d_in[8];
    const float* Wpk = (const float*)d_in[9], *Wpq = (const float*)d_in[10];
    const float* Wo = (const float*)d_in[11], *bo = (const float*)d_in[12];
    const float* g1 = (const float*)d_in[13], *b1ln = (const float*)d_in[14];
    const float* W1 = (const float*)d_in[15], *b1f = (const float*)d_in[16];
    const float* W2 = (const float*)d_in[17], *b2f = (const float*)d_in[18];
    const float* g2 = (const float*)d_in[19], *b2ln = (const float*)d_in[20];
    float* out = (float*)d_out;

    char* w = (char*)d_ws;
    u16*  X16    = (u16*)w;                 w += 12582912;   // [8192,768] bf16
    u16*  pos16  = (u16*)w;                 w += 1572864;    // [1024,768] bf16
    u16*  WqkvT  = (u16*)w;                 w += 3538944;    // [2304,768] bf16
    float* bqkv  = (float*)w;               w += 9216;       // [2304]
    u16*  WoT    = (u16*)w;                 w += 1179648;    // [768,768]
    u16*  W1T    = (u16*)w;                 w += 4718592;    // [3072,768]
    u16*  W2T    = (u16*)w;                 w += 4718592;    // [768,3072]
    u16*  WpkT   = (u16*)w;                 w += 1179648;
    u16*  WpqT   = (u16*)w;                 w += 1179648;    // adjacent to WpkT (merged pos GEMM)
    u16*  posk   = (u16*)w;                 w += 1572864;    // [12][1024][64] bf16 per-head
    u16*  posq   = (u16*)w;                 w += 1572864;    // adjacent to posk (GM_POSH spans both)
    u16*  qkv    = (u16*)w;                 w += 37748736;   // [8192,2304] bf16 (read-only during attn)
    u16*  Vt     = (u16*)w;                 w += 12582912;   // [192,64,512] bf16
    char* big    = w;                       w += 100663296;
    u16*  att16  = (u16*)w;                 w += 12582912;   // [8192,768] bf16 (Wo out; later ffn2 out)
    // lifetime-disjoint carve-up of `big`:
    u16*  ctx  = (u16*)big;                        // [0, 12.6MB)  written by k_attn
    u16*  ffn1 = (u16*)(big + 50331648);           // [48MB, 98.6MB)
    u16*  h1h  = X16;                              // X16 dead after qkv GEMM
    u16*  ffn2 = att16;                            // att16 dead after LN1

    // prep: fused converts + weight transposes + bias pack (one launch)
    TJobs J;
    J.src[0] = Wq;  J.dst[0] = WqkvT;           J.K[0] = 768;  J.N[0] = 768;
    J.src[1] = Wk;  J.dst[1] = WqkvT + 589824;  J.K[1] = 768;  J.N[1] = 768;
    J.src[2] = Wv;  J.dst[2] = WqkvT + 1179648; J.K[2] = 768;  J.N[2] = 768;
    J.src[3] = Wo;  J.dst[3] = WoT;             J.K[3] = 768;  J.N[3] = 768;
    J.src[4] = Wpk; J.dst[4] = WpkT;            J.K[4] = 768;  J.N[4] = 768;
    J.src[5] = Wpq; J.dst[5] = WpqT;            J.K[5] = 768;  J.N[5] = 768;
    J.src[6] = W1;  J.dst[6] = W1T;             J.K[6] = 768;  J.N[6] = 3072;
    J.src[7] = W2;  J.dst[7] = W2T;             J.K[7] = 3072; J.N[7] = 768;
    J.bstart[0] = 0;
    for (int i = 0; i < 8; i++) J.bstart[i + 1] = J.bstart[i] + (J.N[i] >> 5) * (J.K[i] >> 5);
    k_prep<<<J.bstart[8] + 3465, dim3(32, 8), 0, stream>>>(J, hs, X16, pos, pos16, bq, bk, bv, bqkv);

    // merged projections: qkv GEMM (1152 blocks) || pos GEMM (96 blocks) in one launch
    k_gemm_proj<<<1248, 256, 0, stream>>>(X16, WqkvT, bqkv, qkv, pos16, WpkT, posk);

    // fused attention
    k_vt<<<dim3(8, 192), 256, 0, stream>>>(qkv, Vt);
    k_attn<<<dim3(8, 192), 256, 0, stream>>>(qkv, posk, posq, Vt, mask, ctx);
    k_gemm_t<64><<<dim3(12, 64), 256, 0, stream>>>(ctx, WoT, bo, att16, TOK, 768, 768, GM_BF16);
    k_ln_a<<<TOK, 256, 0, stream>>>(hs, att16, g1, b1ln, h1h);

    // FFN (bf16 tail: ffn2 out bf16, LN2 reads bf16 trunk + bf16 ffn2)
    k_gemm_t<128><<<dim3(24, 64), 256, 0, stream>>>(h1h, W1T, b1f, ffn1, TOK, 3072, 768, GM_GELU_BF16);
    k_gemm_t<64><<<dim3(12, 64), 256, 0, stream>>>(ffn1, W2T, b2f, ffn2, TOK, 768, 3072, GM_BF16);
    k_ln_b<<<TOK, 256, 0, stream>>>(h1h, ffn2, g2, b2ln, out);
}